// Round 1
// 292.301 us; speedup vs baseline: 1.0738x; 1.0738x over previous
//
#include <hip/hip_runtime.h>
#include <hip/hip_bf16.h>

#define M_   16384   // B*N tokens
#define K_   1024    // E
#define NQKV 3072    // 3*E output cols

typedef _Float16 f16x4 __attribute__((ext_vector_type(4)));
typedef _Float16 f16x8 __attribute__((ext_vector_type(8)));
typedef float    f32x4 __attribute__((ext_vector_type(4)));

// fp32 -> fp16 grid-stride convert (float4 granularity)
__global__ __launch_bounds__(256) void cvt_f32_f16(const float* __restrict__ in,
                                                   _Float16* __restrict__ o, int n4) {
  int i = blockIdx.x * blockDim.x + threadIdx.x;
  const int stride = gridDim.x * blockDim.x;
  for (; i < n4; i += stride) {
    float4 v = ((const float4*)in)[i];
    f16x4 h; h[0] = (_Float16)v.x; h[1] = (_Float16)v.y;
    h[2] = (_Float16)v.z; h[3] = (_Float16)v.w;
    *(f16x4*)&o[(size_t)i * 4] = h;
  }
}

// 256x256-tile 8-phase GEMM (m201-style template):
//  - 8 waves (512 thr), 2M x 4N wave grid, per-wave output 128x64
//  - BK=64, double-buffered LDS (2 x (A 32KB + B 32KB) = 128 KiB)
//  - XOR swizzle: 16B-block ^= (row&7), applied to global SOURCE of
//    global_load_lds (linear dest) and to ds_read addresses (both-sides rule)
//  - zigzag quadrant phases: (m0,n0)->(m1,n0)->(m1,n1)->(m0,n1), 16 MFMA each,
//    raw s_barrier between phases (no vmcnt drain), setprio(1) around MFMAs
//  - staging for tile t+1 issued in one burst at top of tile t; single
//    vmcnt(0)+barrier at tile end (loads are ~4 phases old by then)
//  - XCD-aware block swizzle: 768 blocks % 8 == 0, each XCD gets 8 contiguous
//    m-tiles x 12 n-tiles (A working set ~4MB = one XCD L2)
__global__ __launch_bounds__(512, 2) void gemm_qkv(
    const _Float16* __restrict__ xh, const _Float16* __restrict__ wh,
    const float* __restrict__ bq, const float* __restrict__ bk,
    const float* __restrict__ bv, _Float16* __restrict__ qkv)
{
  __shared__ __align__(16) _Float16 As[2][256 * 64];
  __shared__ __align__(16) _Float16 Bs[2][256 * 64];

  const int tid  = threadIdx.x;
  const int ln   = tid & 63;
  const int w    = tid >> 6;     // 0..7
  const int wm2  = w >> 2;       // 0..1  (M half: 128 rows)
  const int wn4  = w & 3;        // 0..3  (N quarter: 64 cols)
  const int lcol = ln & 15, quad = ln >> 4;

  const int bid = blockIdx.x;                   // 768 blocks total
  const int swz = (bid & 7) * 96 + (bid >> 3);  // XCD-contiguous chunks
  const int m0 = (swz / 12) * 256;
  const int n0 = (swz % 12) * 256;

  f32x4 acc[8][4];
#pragma unroll
  for (int i = 0; i < 8; ++i)
#pragma unroll
    for (int j = 0; j < 4; ++j) acc[i][j] = f32x4{0.f, 0.f, 0.f, 0.f};

  // Stage one K-tile (A 256x64 + B 256x64 fp16) = 8 global_load_lds / thread.
  // Linear LDS dest slot c = i*512 + tid holds row r=c>>3, 16B-block cb=c&7;
  // source block is cb ^ (r&7)  (inverse-swizzled source, linear dest).
#define STAGE(BUF, T)                                                          \
  {                                                                            \
    const int k0s = (T) * 64;                                                  \
    _Pragma("unroll")                                                          \
    for (int i = 0; i < 4; ++i) {                                              \
      const int c  = i * 512 + tid;                                            \
      const int r  = c >> 3;                                                   \
      const int cb = (c & 7) ^ (r & 7);                                        \
      const int db = (i * 512 + w * 64) * 8; /* wave-uniform elem base */      \
      __builtin_amdgcn_global_load_lds(                                        \
          (const __attribute__((address_space(1))) void*)(                     \
              xh + (size_t)(m0 + r) * K_ + k0s + cb * 8),                      \
          (__attribute__((address_space(3))) void*)(&As[BUF][db]), 16, 0, 0);  \
      __builtin_amdgcn_global_load_lds(                                        \
          (const __attribute__((address_space(1))) void*)(                     \
              wh + (size_t)(n0 + r) * K_ + k0s + cb * 8),                      \
          (__attribute__((address_space(3))) void*)(&Bs[BUF][db]), 16, 0, 0);  \
    }                                                                          \
  }

  f16x8 a[4][2], b[2][2];

  // swizzled ds_read of A fragments for m-half MH (8 x ds_read_b128)
#define LOADA(MH)                                                              \
  _Pragma("unroll")                                                            \
  for (int mi = 0; mi < 4; ++mi) {                                             \
    const int ar = wm2 * 128 + (MH) * 64 + mi * 16 + lcol;                     \
    const int sw = ar & 7;                                                     \
    a[mi][0] = *(const f16x8*)&As[cur][ar * 64 + ((quad    ) ^ sw) * 8];       \
    a[mi][1] = *(const f16x8*)&As[cur][ar * 64 + ((quad + 4) ^ sw) * 8];       \
  }

  // swizzled ds_read of B fragments for n-half NH (4 x ds_read_b128)
#define LOADB(NH)                                                              \
  _Pragma("unroll")                                                            \
  for (int ni = 0; ni < 2; ++ni) {                                             \
    const int br = wn4 * 64 + (NH) * 32 + ni * 16 + lcol;                      \
    const int sw = br & 7;                                                     \
    b[ni][0] = *(const f16x8*)&Bs[cur][br * 64 + ((quad    ) ^ sw) * 8];       \
    b[ni][1] = *(const f16x8*)&Bs[cur][br * 64 + ((quad + 4) ^ sw) * 8];       \
  }

  // one C-quadrant x K=64: 16 MFMAs
#define MFMA16(MH, NH)                                                         \
  __builtin_amdgcn_s_setprio(1);                                               \
  _Pragma("unroll")                                                            \
  for (int kb = 0; kb < 2; ++kb)                                               \
    _Pragma("unroll")                                                          \
    for (int mi = 0; mi < 4; ++mi)                                             \
      _Pragma("unroll")                                                        \
      for (int ni = 0; ni < 2; ++ni)                                           \
        acc[(MH) * 4 + mi][(NH) * 2 + ni] =                                    \
            __builtin_amdgcn_mfma_f32_16x16x32_f16(                            \
                a[mi][kb], b[ni][kb], acc[(MH) * 4 + mi][(NH) * 2 + ni],       \
                0, 0, 0);                                                      \
  __builtin_amdgcn_s_setprio(0);

  // prologue: stage tile 0, drain, barrier
  STAGE(0, 0);
  asm volatile("s_waitcnt vmcnt(0)" ::: "memory");
  __builtin_amdgcn_s_barrier();

  for (int t = 0; t < 16; ++t) {
    const int cur = t & 1;
    if (t < 15) STAGE(cur ^ 1, t + 1);   // burst-issue next tile's 8 loads

    LOADA(0); LOADB(0); MFMA16(0, 0);
    __builtin_amdgcn_s_barrier(); __builtin_amdgcn_sched_barrier(0);
    LOADA(1);           MFMA16(1, 0);    // reuse b
    __builtin_amdgcn_s_barrier(); __builtin_amdgcn_sched_barrier(0);
              LOADB(1); MFMA16(1, 1);    // reuse a
    __builtin_amdgcn_s_barrier(); __builtin_amdgcn_sched_barrier(0);
    LOADA(0);           MFMA16(0, 1);    // reuse b
    if (t < 15) asm volatile("s_waitcnt vmcnt(0)" ::: "memory");
    __builtin_amdgcn_s_barrier(); __builtin_amdgcn_sched_barrier(0);
  }

  // Epilogue: C/D col=lane&15, row=quad*4+reg. qkv[token*3072 + col].
#pragma unroll
  for (int nh = 0; nh < 4; ++nh) {
    const int col = n0 + wn4 * 64 + nh * 16 + lcol;
    const int seg = col >> 10, cs = col & 1023;
    const float bi = ((seg == 0) ? bq : (seg == 1) ? bk : bv)[cs];
#pragma unroll
    for (int mi = 0; mi < 8; ++mi) {
      const int r0 = m0 + wm2 * 128 + mi * 16 + quad * 4;
#pragma unroll
      for (int r = 0; r < 4; ++r)
        qkv[(size_t)(r0 + r) * 3072 + col] = (_Float16)(acc[mi][nh][r] + bi);
    }
  }
#undef STAGE
#undef LOADA
#undef LOADB
#undef MFMA16
}

// One wave per token. qkv [token][3][1024] fp16. MFMA micro-attention with
// V staged transposed through wave-private LDS (no scalar global loads).
__global__ __launch_bounds__(256) void attn_kernel(
    const _Float16* __restrict__ qkv,
    const float* __restrict__ pat,
    float* __restrict__ out)
{
  __shared__ float pat_s[256];
  __shared__ __align__(16) _Float16 Ps[4][16 * 24];  // P[h][g], stride 24
  __shared__ __align__(16) _Float16 Vt[4][64 * 24];  // V^T[d][g], stride 24

  const int tid  = threadIdx.x;
  const int ln   = tid & 63;
  const int wv   = tid >> 6;
  const int lcol = ln & 15, quad = ln >> 4;
  const int t    = blockIdx.x * 4 + wv;

  pat_s[tid] = pat[tid];
  __syncthreads();

  const _Float16* qg = qkv + (size_t)t * 3072;
  const _Float16* kg = qg + 1024;
  const _Float16* vg = qg + 2048;

  // Stage V transposed: coalesced f16x8 reads, scatter to Vt[d][g].
#pragma unroll
  for (int i = 0; i < 2; i++) {
    const int e = i * 64 + ln;           // chunk 0..127 over V[16][64]
    const int g = e >> 3, c = (e & 7) * 8;
    f16x8 vc = *(const f16x8*)(vg + g * 64 + c);
#pragma unroll
    for (int j = 0; j < 8; j++) Vt[wv][(c + j) * 24 + g] = vc[j];
  }

  // QK^T: A[m=h=lcol][k=quad*8+j], B[n=g=lcol][k=quad*8+j]
  f16x8 aq0 = *(const f16x8*)(qg + lcol * 64 + quad * 8);
  f16x8 aq1 = *(const f16x8*)(qg + lcol * 64 + 32 + quad * 8);
  f16x8 bk0 = *(const f16x8*)(kg + lcol * 64 + quad * 8);
  f16x8 bk1 = *(const f16x8*)(kg + lcol * 64 + 32 + quad * 8);
  f32x4 s = {0.f, 0.f, 0.f, 0.f};
  s = __builtin_amdgcn_mfma_f32_16x16x32_f16(aq0, bk0, s, 0, 0, 0);
  s = __builtin_amdgcn_mfma_f32_16x16x32_f16(aq1, bk1, s, 0, 0, 0);

  // lane holds scores[h=quad*4+r][g=lcol]; mask, softmax over g (16 lanes)
#pragma unroll
  for (int r = 0; r < 4; r++) {
    const float sv = s[r] * pat_s[(quad * 4 + r) * 16 + lcol];
    float m = sv;
#pragma unroll
    for (int msk = 1; msk < 16; msk <<= 1) m = fmaxf(m, __shfl_xor(m, msk, 64));
    const float e = __expf(sv - m);
    float su = e;
#pragma unroll
    for (int msk = 1; msk < 16; msk <<= 1) su += __shfl_xor(su, msk, 64);
    Ps[wv][(quad * 4 + r) * 24 + lcol] = (_Float16)(e / su);
  }

  // PV: A[m=h=lcol][k=g=quad*8+j] from Ps; B[n=d][k=g] from Vt. k>=16 zero.
  f16x8 ap = {};
  if (quad < 2) ap = *(const f16x8*)&Ps[wv][lcol * 24 + quad * 8];

  f32x4 o[4];
#pragma unroll
  for (int dt = 0; dt < 4; dt++) {
    f16x8 bvf = {};
    if (quad < 2) bvf = *(const f16x8*)&Vt[wv][(dt * 16 + lcol) * 24 + quad * 8];
    f32x4 z = {0.f, 0.f, 0.f, 0.f};
    o[dt] = __builtin_amdgcn_mfma_f32_16x16x32_f16(ap, bvf, z, 0, 0, 0);
  }

  // C layout: row h=quad*4+r, col d=dt*16+lcol
  float* op = out + (size_t)t * 1024;
#pragma unroll
  for (int dt = 0; dt < 4; dt++)
#pragma unroll
    for (int r = 0; r < 4; r++)
      op[(quad * 4 + r) * 64 + dt * 16 + lcol] = o[dt][r];
}

extern "C" void kernel_launch(void* const* d_in, const int* in_sizes, int n_in,
                              void* d_out, int out_size, void* d_ws, size_t ws_size,
                              hipStream_t stream) {
  const float* x   = (const float*)d_in[0];
  const float* pat = (const float*)d_in[1];
  const float* Wq  = (const float*)d_in[2];
  const float* bq  = (const float*)d_in[3];
  const float* Wk  = (const float*)d_in[4];
  const float* bk  = (const float*)d_in[5];
  const float* Wv  = (const float*)d_in[6];
  const float* bv  = (const float*)d_in[7];

  // ws layout (f16 elements):
  //   qkvh [16384][3][1024]  @ 0           (96 MiB)
  //   xh   [16384][1024]     @ 50331648    (32 MiB)
  //   wh   [3][1024][1024]   @ 67108864    ( 6 MiB)   total ~134 MiB
  _Float16* qkvh = (_Float16*)d_ws;
  _Float16* xh   = qkvh + (size_t)50331648;
  _Float16* wh   = qkvh + (size_t)67108864;

  cvt_f32_f16<<<4096, 256, 0, stream>>>(x,  xh,               4194304);
  cvt_f32_f16<<<1024, 256, 0, stream>>>(Wq, wh,                262144);
  cvt_f32_f16<<<1024, 256, 0, stream>>>(Wk, wh + 1048576,      262144);
  cvt_f32_f16<<<1024, 256, 0, stream>>>(Wv, wh + 2097152,      262144);

  // 64 m-tiles x 12 n-tiles = 768 blocks, 512 threads (8 waves)
  gemm_qkv<<<768, 512, 0, stream>>>(xh, wh, bq, bk, bv, qkvh);
  attn_kernel<<<M_ / 4, 256, 0, stream>>>(qkvh, pat, (float*)d_out);
}

// Round 2
// 283.540 us; speedup vs baseline: 1.1070x; 1.0309x over previous
//
#include <hip/hip_runtime.h>
#include <hip/hip_bf16.h>

#define M_   16384   // B*N tokens
#define K_   1024    // E
#define NQKV 3072    // 3*E output cols

typedef _Float16 f16x4 __attribute__((ext_vector_type(4)));
typedef _Float16 f16x8 __attribute__((ext_vector_type(8)));
typedef float    f32x4 __attribute__((ext_vector_type(4)));

// fp32 -> fp16 grid-stride convert (float4 granularity)
__global__ __launch_bounds__(256) void cvt_f32_f16(const float* __restrict__ in,
                                                   _Float16* __restrict__ o, int n4) {
  int i = blockIdx.x * blockDim.x + threadIdx.x;
  const int stride = gridDim.x * blockDim.x;
  for (; i < n4; i += stride) {
    float4 v = ((const float4*)in)[i];
    f16x4 h; h[0] = (_Float16)v.x; h[1] = (_Float16)v.y;
    h[2] = (_Float16)v.z; h[3] = (_Float16)v.w;
    *(f16x4*)&o[(size_t)i * 4] = h;
  }
}

// 3 weight matrices in one launch (blockIdx.y selects source)
__global__ __launch_bounds__(256) void cvt3_f32_f16(
    const float* __restrict__ a, const float* __restrict__ b,
    const float* __restrict__ c, _Float16* __restrict__ o, int n4each) {
  const float* src = (blockIdx.y == 0) ? a : (blockIdx.y == 1) ? b : c;
  _Float16* dst = o + (size_t)blockIdx.y * n4each * 4;
  int i = blockIdx.x * blockDim.x + threadIdx.x;
  const int stride = gridDim.x * blockDim.x;
  for (; i < n4each; i += stride) {
    float4 v = ((const float4*)src)[i];
    f16x4 h; h[0] = (_Float16)v.x; h[1] = (_Float16)v.y;
    h[2] = (_Float16)v.z; h[3] = (_Float16)v.w;
    *(f16x4*)&dst[(size_t)i * 4] = h;
  }
}

// 256x256-tile 8-phase GEMM with COUNTED vmcnt (T3+T4+T2+T5+T1):
//  - 8 waves, per-wave 128x64 out; BK=64; double-buffered LDS (128 KiB)
//  - staging split into half-tiles (2 gload_lds each), 1 per phase:
//      ph1: buf1.A-h0 (kt+1)   ph5: buf0.A-h0 (kt+2)
//      ph2: buf0.B-h0 (kt+2)   ph6: buf1.B-h0 (kt+3)
//      ph3: buf0.A-h1 (kt+2)   ph7: buf1.A-h1 (kt+3)
//      ph4: buf0.B-h1 (kt+2)   ph8: buf1.B-h1 (kt+3)
//    each region overwritten >=1 phase after its last read (barrier-separated)
//    and its data guaranteed by the counted waits below before next read.
//  - s_waitcnt vmcnt(6) ONLY at ph4 and ph8 (3 half-tiles stay in flight);
//    last iteration: vmcnt(0) at ph4, no ph8 wait.
//  - A-halves match LOADA read sets: A-hX = rows {X*64..X*64+63} u {128+X*64..}
//    B-halves match LOADB: B-hY = rows {q*64+Y*32 .. +31} for q=0..3
//  - XOR swizzle both-sides (src pre-swizzle + swizzled ds_read), linear dest
//  - per phase: ds_reads | stage -> barrier -> lgkmcnt(0)+sched_barrier ->
//    setprio(1) 16xMFMA setprio(0) -> barrier
__global__ __launch_bounds__(512, 2) void gemm_qkv(
    const _Float16* __restrict__ xh, const _Float16* __restrict__ wh,
    const float* __restrict__ bq, const float* __restrict__ bk,
    const float* __restrict__ bv, _Float16* __restrict__ qkv)
{
  __shared__ __align__(16) _Float16 As[2][256 * 64];
  __shared__ __align__(16) _Float16 Bs[2][256 * 64];

  const int tid  = threadIdx.x;
  const int ln   = tid & 63;
  const int w    = tid >> 6;     // 0..7
  const int wm2  = w >> 2;       // 0..1
  const int wn4  = w & 3;        // 0..3
  const int lcol = ln & 15, quad = ln >> 4;

  const int bid = blockIdx.x;                   // 768 blocks
  const int swz = (bid & 7) * 96 + (bid >> 3);  // XCD-contiguous chunks
  const int m0 = (swz / 12) * 256;
  const int n0 = (swz % 12) * 256;

  f32x4 acc[8][4];
#pragma unroll
  for (int i = 0; i < 8; ++i)
#pragma unroll
    for (int j = 0; j < 4; ++j) acc[i][j] = f32x4{0.f, 0.f, 0.f, 0.f};

  f16x8 a[4][2], b[2][2];

  // ---- staging: one half-tile = 128 rows x 64 cols of one matrix = 2 loads.
  // dest is the wave-uniform LDS base (HW adds lane*16); source row/block are
  // per-lane with inverse swizzle cb = (c&7)^(r&7).
#define STAGE_A(BUF, KT, X)                                                    \
  { _Pragma("unroll")                                                          \
    for (int j = 0; j < 2; ++j) {                                              \
      const int c   = j * 512 + tid;                                           \
      const int rr  = c >> 3;                                                  \
      const int r   = (X) * 64 + (rr & 63) + ((rr >> 6) << 7);                 \
      const int cb  = (c & 7) ^ (r & 7);                                       \
      const int rr0 = j * 64 + w * 8;                                          \
      const int r0  = (X) * 64 + (rr0 & 63) + ((rr0 >> 6) << 7);               \
      __builtin_amdgcn_global_load_lds(                                        \
          (const __attribute__((address_space(1))) void*)(                     \
              xh + (size_t)(m0 + r) * K_ + (KT) * 64 + cb * 8),                \
          (__attribute__((address_space(3))) void*)(&As[BUF][r0 * 64]),        \
          16, 0, 0);                                                           \
    } }

#define STAGE_B(BUF, KT, Y)                                                    \
  { _Pragma("unroll")                                                          \
    for (int j = 0; j < 2; ++j) {                                              \
      const int c   = j * 512 + tid;                                           \
      const int rr  = c >> 3;                                                  \
      const int r   = ((rr >> 5) << 6) + (Y) * 32 + (rr & 31);                 \
      const int cb  = (c & 7) ^ (r & 7);                                       \
      const int rr0 = j * 64 + w * 8;                                          \
      const int r0  = ((rr0 >> 5) << 6) + (Y) * 32 + (rr0 & 31);               \
      __builtin_amdgcn_global_load_lds(                                        \
          (const __attribute__((address_space(1))) void*)(                     \
              wh + (size_t)(n0 + r) * K_ + (KT) * 64 + cb * 8),                \
          (__attribute__((address_space(3))) void*)(&Bs[BUF][r0 * 64]),        \
          16, 0, 0);                                                           \
    } }

#define LOADA(BUF, MH)                                                         \
  _Pragma("unroll")                                                            \
  for (int mi = 0; mi < 4; ++mi) {                                             \
    const int ar = wm2 * 128 + (MH) * 64 + mi * 16 + lcol;                     \
    const int sw = ar & 7;                                                     \
    a[mi][0] = *(const f16x8*)&As[BUF][ar * 64 + ((quad    ) ^ sw) * 8];       \
    a[mi][1] = *(const f16x8*)&As[BUF][ar * 64 + ((quad + 4) ^ sw) * 8];       \
  }

#define LOADB(BUF, NH)                                                         \
  _Pragma("unroll")                                                            \
  for (int ni = 0; ni < 2; ++ni) {                                             \
    const int br = wn4 * 64 + (NH) * 32 + ni * 16 + lcol;                      \
    const int sw = br & 7;                                                     \
    b[ni][0] = *(const f16x8*)&Bs[BUF][br * 64 + ((quad    ) ^ sw) * 8];       \
    b[ni][1] = *(const f16x8*)&Bs[BUF][br * 64 + ((quad + 4) ^ sw) * 8];       \
  }

#define MFMA16(MH, NH)                                                         \
  __builtin_amdgcn_s_setprio(1);                                               \
  _Pragma("unroll")                                                            \
  for (int kb = 0; kb < 2; ++kb)                                               \
    _Pragma("unroll")                                                          \
    for (int mi = 0; mi < 4; ++mi)                                             \
      _Pragma("unroll")                                                        \
      for (int ni = 0; ni < 2; ++ni)                                           \
        acc[(MH) * 4 + mi][(NH) * 2 + ni] =                                    \
            __builtin_amdgcn_mfma_f32_16x16x32_f16(                            \
                a[mi][kb], b[ni][kb], acc[(MH) * 4 + mi][(NH) * 2 + ni],       \
                0, 0, 0);                                                      \
  __builtin_amdgcn_s_setprio(0);

#define BAR()  { __builtin_amdgcn_s_barrier(); __builtin_amdgcn_sched_barrier(0); }
#define LGKM0() { asm volatile("s_waitcnt lgkmcnt(0)" ::: "memory");           \
                  __builtin_amdgcn_sched_barrier(0); }
#define VM6() asm volatile("s_waitcnt vmcnt(6)" ::: "memory")
#define VM0() asm volatile("s_waitcnt vmcnt(0)" ::: "memory")

  // One iteration: phases 1-4 compute buf0 (K-tile kt0), 5-8 buf1 (kt0+1).
  // Zigzag quadrants per buffer: (0,0)->(1,0)->(1,1)->(0,1) with a/b reuse.
#define GITER(KT0, LAST)                                                       \
  { /* ph1 */                                                                  \
    LOADA(0, 0); LOADB(0, 0); STAGE_A(1, (KT0) + 1, 0);                        \
    BAR(); LGKM0(); MFMA16(0, 0); BAR();                                       \
    /* ph2 */                                                                  \
    LOADA(0, 1); if (!(LAST)) STAGE_B(0, (KT0) + 2, 0);                        \
    BAR(); LGKM0(); MFMA16(1, 0); BAR();                                       \
    /* ph3 */                                                                  \
    LOADB(0, 1); if (!(LAST)) STAGE_A(0, (KT0) + 2, 1);                        \
    BAR(); LGKM0(); MFMA16(1, 1); BAR();                                       \
    /* ph4 */                                                                  \
    LOADA(0, 0); if (!(LAST)) STAGE_B(0, (KT0) + 2, 1);                        \
    if (LAST) { VM0(); } else { VM6(); }                                       \
    BAR(); LGKM0(); MFMA16(0, 1); BAR();                                       \
    /* ph5 */                                                                  \
    LOADA(1, 0); LOADB(1, 0); if (!(LAST)) STAGE_A(0, (KT0) + 2, 0);           \
    BAR(); LGKM0(); MFMA16(0, 0); BAR();                                       \
    /* ph6 */                                                                  \
    LOADA(1, 1); if (!(LAST)) STAGE_B(1, (KT0) + 3, 0);                        \
    BAR(); LGKM0(); MFMA16(1, 0); BAR();                                       \
    /* ph7 */                                                                  \
    LOADB(1, 1); if (!(LAST)) STAGE_A(1, (KT0) + 3, 1);                        \
    BAR(); LGKM0(); MFMA16(1, 1); BAR();                                       \
    /* ph8 */                                                                  \
    LOADA(1, 0); if (!(LAST)) { STAGE_B(1, (KT0) + 3, 1); VM6(); }             \
    BAR(); LGKM0(); MFMA16(0, 1); BAR();                                       \
  }

  // Prologue: buf0 = kt0 full (4 half-tiles), buf1 = kt1 {B-h0, A-h1, B-h1}
  // (buf1.A-h0 arrives at ph1 of iter 0). Wait buf0 (vmcnt(6) leaves buf1's 3).
  STAGE_A(0, 0, 0); STAGE_B(0, 0, 0); STAGE_A(0, 0, 1); STAGE_B(0, 0, 1);
  STAGE_B(1, 1, 0); STAGE_A(1, 1, 1); STAGE_B(1, 1, 1);
  VM6(); BAR();

#pragma unroll 1
  for (int it = 0; it < 7; ++it) { GITER(it * 2, 0); }
  GITER(14, 1);

  // Epilogue: C/D col=lane&15, row=quad*4+reg. qkv[token*3072 + col].
#pragma unroll
  for (int nh = 0; nh < 4; ++nh) {
    const int col = n0 + wn4 * 64 + nh * 16 + lcol;
    const int seg = col >> 10, cs = col & 1023;
    const float bi = ((seg == 0) ? bq : (seg == 1) ? bk : bv)[cs];
#pragma unroll
    for (int mi = 0; mi < 8; ++mi) {
      const int r0 = m0 + wm2 * 128 + mi * 16 + quad * 4;
#pragma unroll
      for (int r = 0; r < 4; ++r)
        qkv[(size_t)(r0 + r) * 3072 + col] = (_Float16)(acc[mi][nh][r] + bi);
    }
  }
#undef STAGE_A
#undef STAGE_B
#undef LOADA
#undef LOADB
#undef MFMA16
#undef BAR
#undef LGKM0
#undef VM6
#undef VM0
#undef GITER
}

// One wave per token. qkv [token][3][1024] fp16. MFMA micro-attention with
// V staged transposed through wave-private LDS (no scalar global loads).
__global__ __launch_bounds__(256) void attn_kernel(
    const _Float16* __restrict__ qkv,
    const float* __restrict__ pat,
    float* __restrict__ out)
{
  __shared__ float pat_s[256];
  __shared__ __align__(16) _Float16 Ps[4][16 * 24];  // P[h][g], stride 24
  __shared__ __align__(16) _Float16 Vt[4][64 * 24];  // V^T[d][g], stride 24

  const int tid  = threadIdx.x;
  const int ln   = tid & 63;
  const int wv   = tid >> 6;
  const int lcol = ln & 15, quad = ln >> 4;
  const int t    = blockIdx.x * 4 + wv;

  pat_s[tid] = pat[tid];
  __syncthreads();

  const _Float16* qg = qkv + (size_t)t * 3072;
  const _Float16* kg = qg + 1024;
  const _Float16* vg = qg + 2048;

  // Stage V transposed: coalesced f16x8 reads, scatter to Vt[d][g].
#pragma unroll
  for (int i = 0; i < 2; i++) {
    const int e = i * 64 + ln;           // chunk 0..127 over V[16][64]
    const int g = e >> 3, c = (e & 7) * 8;
    f16x8 vc = *(const f16x8*)(vg + g * 64 + c);
#pragma unroll
    for (int j = 0; j < 8; j++) Vt[wv][(c + j) * 24 + g] = vc[j];
  }

  // QK^T: A[m=h=lcol][k=quad*8+j], B[n=g=lcol][k=quad*8+j]
  f16x8 aq0 = *(const f16x8*)(qg + lcol * 64 + quad * 8);
  f16x8 aq1 = *(const f16x8*)(qg + lcol * 64 + 32 + quad * 8);
  f16x8 bk0 = *(const f16x8*)(kg + lcol * 64 + quad * 8);
  f16x8 bk1 = *(const f16x8*)(kg + lcol * 64 + 32 + quad * 8);
  f32x4 s = {0.f, 0.f, 0.f, 0.f};
  s = __builtin_amdgcn_mfma_f32_16x16x32_f16(aq0, bk0, s, 0, 0, 0);
  s = __builtin_amdgcn_mfma_f32_16x16x32_f16(aq1, bk1, s, 0, 0, 0);

  // lane holds scores[h=quad*4+r][g=lcol]; mask, softmax over g (16 lanes)
#pragma unroll
  for (int r = 0; r < 4; r++) {
    const float sv = s[r] * pat_s[(quad * 4 + r) * 16 + lcol];
    float m = sv;
#pragma unroll
    for (int msk = 1; msk < 16; msk <<= 1) m = fmaxf(m, __shfl_xor(m, msk, 64));
    const float e = __expf(sv - m);
    float su = e;
#pragma unroll
    for (int msk = 1; msk < 16; msk <<= 1) su += __shfl_xor(su, msk, 64);
    Ps[wv][(quad * 4 + r) * 24 + lcol] = (_Float16)(e / su);
  }

  // PV: A[m=h=lcol][k=g=quad*8+j] from Ps; B[n=d][k=g] from Vt. k>=16 zero.
  f16x8 ap = {};
  if (quad < 2) ap = *(const f16x8*)&Ps[wv][lcol * 24 + quad * 8];

  f32x4 o[4];
#pragma unroll
  for (int dt = 0; dt < 4; dt++) {
    f16x8 bvf = {};
    if (quad < 2) bvf = *(const f16x8*)&Vt[wv][(dt * 16 + lcol) * 24 + quad * 8];
    f32x4 z = {0.f, 0.f, 0.f, 0.f};
    o[dt] = __builtin_amdgcn_mfma_f32_16x16x32_f16(ap, bvf, z, 0, 0, 0);
  }

  // C layout: row h=quad*4+r, col d=dt*16+lcol
  float* op = out + (size_t)t * 1024;
#pragma unroll
  for (int dt = 0; dt < 4; dt++)
#pragma unroll
    for (int r = 0; r < 4; r++)
      op[(quad * 4 + r) * 64 + dt * 16 + lcol] = o[dt][r];
}

extern "C" void kernel_launch(void* const* d_in, const int* in_sizes, int n_in,
                              void* d_out, int out_size, void* d_ws, size_t ws_size,
                              hipStream_t stream) {
  const float* x   = (const float*)d_in[0];
  const float* pat = (const float*)d_in[1];
  const float* Wq  = (const float*)d_in[2];
  const float* bq  = (const float*)d_in[3];
  const float* Wk  = (const float*)d_in[4];
  const float* bk  = (const float*)d_in[5];
  const float* Wv  = (const float*)d_in[6];
  const float* bv  = (const float*)d_in[7];

  // ws layout (f16 elements):
  //   qkvh [16384][3][1024]  @ 0           (96 MiB)
  //   xh   [16384][1024]     @ 50331648    (32 MiB)
  //   wh   [3][1024][1024]   @ 67108864    ( 6 MiB)   total ~134 MiB
  _Float16* qkvh = (_Float16*)d_ws;
  _Float16* xh   = qkvh + (size_t)50331648;
  _Float16* wh   = qkvh + (size_t)67108864;

  cvt_f32_f16<<<4096, 256, 0, stream>>>(x, xh, 4194304);
  cvt3_f32_f16<<<dim3(256, 3), 256, 0, stream>>>(Wq, Wk, Wv, wh, 262144);

  // 64 m-tiles x 12 n-tiles = 768 blocks, 512 threads (8 waves)
  gemm_qkv<<<768, 512, 0, stream>>>(xh, wh, bq, bk, bv, qkvh);
  attn_kernel<<<M_ / 4, 256, 0, stream>>>(qkvh, pat, (float*)d_out);
}

// Round 3
// 271.863 us; speedup vs baseline: 1.1546x; 1.0430x over previous
//
#include <hip/hip_runtime.h>
#include <hip/hip_bf16.h>

#define M_   16384   // B*N tokens
#define K_   1024    // E
#define NQKV 3072    // 3*E output cols

typedef _Float16 f16x4 __attribute__((ext_vector_type(4)));
typedef _Float16 f16x8 __attribute__((ext_vector_type(8)));
typedef float    f32x4 __attribute__((ext_vector_type(4)));

// fp32 -> fp16 grid-stride convert (float4 granularity)
__global__ __launch_bounds__(256) void cvt_f32_f16(const float* __restrict__ in,
                                                   _Float16* __restrict__ o, int n4) {
  int i = blockIdx.x * blockDim.x + threadIdx.x;
  const int stride = gridDim.x * blockDim.x;
  for (; i < n4; i += stride) {
    float4 v = ((const float4*)in)[i];
    f16x4 h; h[0] = (_Float16)v.x; h[1] = (_Float16)v.y;
    h[2] = (_Float16)v.z; h[3] = (_Float16)v.w;
    *(f16x4*)&o[(size_t)i * 4] = h;
  }
}

// 3 weight matrices in one launch (blockIdx.y selects source)
__global__ __launch_bounds__(256) void cvt3_f32_f16(
    const float* __restrict__ a, const float* __restrict__ b,
    const float* __restrict__ c, _Float16* __restrict__ o, int n4each) {
  const float* src = (blockIdx.y == 0) ? a : (blockIdx.y == 1) ? b : c;
  _Float16* dst = o + (size_t)blockIdx.y * n4each * 4;
  int i = blockIdx.x * blockDim.x + threadIdx.x;
  const int stride = gridDim.x * blockDim.x;
  for (; i < n4each; i += stride) {
    float4 v = ((const float4*)src)[i];
    f16x4 h; h[0] = (_Float16)v.x; h[1] = (_Float16)v.y;
    h[2] = (_Float16)v.z; h[3] = (_Float16)v.w;
    *(f16x4*)&dst[(size_t)i * 4] = h;
  }
}

// 256x256-tile 8-phase GEMM, counted vmcnt AND counted lgkmcnt.
// Fragment regs: a0/a1 (both A halves kept -> no re-read; 24 ds_read/wave/K-tile,
// the minimum), b0/b1. Phase reads: ph1{B0,A0}=12, ph2{A1}=8, ph3{B1}=4, ph4{0}.
// Each phase: issue kb0 reads | kb1 reads | stage -> barrier -> lgkmcnt(N) ->
// 8 MFMA (kb0) -> lgkmcnt(0) -> 8 MFMA (kb1) -> barrier. ph4 is pure MFMA.
// Stage schedule + vmcnt(6)@ph4/ph8 ledger identical to prior round (verified).
__global__ __launch_bounds__(512, 2) void gemm_qkv(
    const _Float16* __restrict__ xh, const _Float16* __restrict__ wh,
    const float* __restrict__ bq, const float* __restrict__ bk,
    const float* __restrict__ bv, _Float16* __restrict__ qkv)
{
  __shared__ __align__(16) _Float16 As[2][256 * 64];
  __shared__ __align__(16) _Float16 Bs[2][256 * 64];

  const int tid  = threadIdx.x;
  const int ln   = tid & 63;
  const int w    = tid >> 6;     // 0..7
  const int wm2  = w >> 2;       // 0..1
  const int wn4  = w & 3;        // 0..3
  const int lcol = ln & 15, quad = ln >> 4;

  const int bid = blockIdx.x;                   // 768 blocks
  const int swz = (bid & 7) * 96 + (bid >> 3);  // XCD-contiguous chunks
  const int m0 = (swz / 12) * 256;
  const int n0 = (swz % 12) * 256;

  f32x4 acc[8][4];
#pragma unroll
  for (int i = 0; i < 8; ++i)
#pragma unroll
    for (int j = 0; j < 4; ++j) acc[i][j] = f32x4{0.f, 0.f, 0.f, 0.f};

  f16x8 a0[4][2], a1[4][2], b0[2][2], b1[2][2];

#define STAGE_A(BUF, KT, X)                                                    \
  { _Pragma("unroll")                                                          \
    for (int j = 0; j < 2; ++j) {                                              \
      const int c   = j * 512 + tid;                                           \
      const int rr  = c >> 3;                                                  \
      const int r   = (X) * 64 + (rr & 63) + ((rr >> 6) << 7);                 \
      const int cb  = (c & 7) ^ (r & 7);                                       \
      const int rr0 = j * 64 + w * 8;                                          \
      const int r0  = (X) * 64 + (rr0 & 63) + ((rr0 >> 6) << 7);               \
      __builtin_amdgcn_global_load_lds(                                        \
          (const __attribute__((address_space(1))) void*)(                     \
              xh + (size_t)(m0 + r) * K_ + (KT) * 64 + cb * 8),                \
          (__attribute__((address_space(3))) void*)(&As[BUF][r0 * 64]),        \
          16, 0, 0);                                                           \
    } }

#define STAGE_B(BUF, KT, Y)                                                    \
  { _Pragma("unroll")                                                          \
    for (int j = 0; j < 2; ++j) {                                              \
      const int c   = j * 512 + tid;                                           \
      const int rr  = c >> 3;                                                  \
      const int r   = ((rr >> 5) << 6) + (Y) * 32 + (rr & 31);                 \
      const int cb  = (c & 7) ^ (r & 7);                                       \
      const int rr0 = j * 64 + w * 8;                                          \
      const int r0  = ((rr0 >> 5) << 6) + (Y) * 32 + (rr0 & 31);               \
      __builtin_amdgcn_global_load_lds(                                        \
          (const __attribute__((address_space(1))) void*)(                     \
              wh + (size_t)(n0 + r) * K_ + (KT) * 64 + cb * 8),                \
          (__attribute__((address_space(3))) void*)(&Bs[BUF][r0 * 64]),        \
          16, 0, 0);                                                           \
    } }

  // fragment reads, per k-block KB (0/1): A = 4 ds_read_b128, B = 2
#define RDA(DST, BUF, MH, KB)                                                  \
  _Pragma("unroll")                                                            \
  for (int mi = 0; mi < 4; ++mi) {                                             \
    const int ar = wm2 * 128 + (MH) * 64 + mi * 16 + lcol;                     \
    const int sw = ar & 7;                                                     \
    DST[mi][KB] = *(const f16x8*)&As[BUF][ar * 64 + (((KB)*4 + quad) ^ sw) * 8]; \
  }

#define RDB(DST, BUF, NH, KB)                                                  \
  _Pragma("unroll")                                                            \
  for (int ni = 0; ni < 2; ++ni) {                                             \
    const int br = wn4 * 64 + (NH) * 32 + ni * 16 + lcol;                      \
    const int sw = br & 7;                                                     \
    DST[ni][KB] = *(const f16x8*)&Bs[BUF][br * 64 + (((KB)*4 + quad) ^ sw) * 8]; \
  }

#define MFMA8(AARR, BARR, MH, NH, KB)                                          \
  __builtin_amdgcn_s_setprio(1);                                               \
  _Pragma("unroll")                                                            \
  for (int mi = 0; mi < 4; ++mi)                                               \
    _Pragma("unroll")                                                          \
    for (int ni = 0; ni < 2; ++ni)                                             \
      acc[(MH) * 4 + mi][(NH) * 2 + ni] =                                      \
          __builtin_amdgcn_mfma_f32_16x16x32_f16(                              \
              AARR[mi][KB], BARR[ni][KB], acc[(MH) * 4 + mi][(NH) * 2 + ni],   \
              0, 0, 0);                                                        \
  __builtin_amdgcn_s_setprio(0);

#define SB()    __builtin_amdgcn_sched_barrier(0)
#define BAR()   { __builtin_amdgcn_s_barrier(); SB(); }
#define LGKM(N) { asm volatile("s_waitcnt lgkmcnt(" #N ")" ::: "memory"); SB(); }
#define VM6()   asm volatile("s_waitcnt vmcnt(6)" ::: "memory")
#define VM0()   asm volatile("s_waitcnt vmcnt(0)" ::: "memory")

  // 4 phases for one K-tile in BUF; STG1..4 are the stage ops for each phase.
#define KTILE(BUF, STG1, STG2, STG3, STG4, WAIT4)                              \
  { /* ph1: B0 + A0 (12 reads) */                                              \
    RDB(b0, BUF, 0, 0); RDA(a0, BUF, 0, 0); SB();                              \
    RDB(b0, BUF, 0, 1); RDA(a0, BUF, 0, 1); SB();                              \
    STG1;                                                                      \
    BAR(); LGKM(6);  MFMA8(a0, b0, 0, 0, 0);                                   \
           LGKM(0);  MFMA8(a0, b0, 0, 0, 1); BAR();                            \
    /* ph2: A1 (8 reads) */                                                    \
    RDA(a1, BUF, 1, 0); SB(); RDA(a1, BUF, 1, 1); SB();                        \
    STG2;                                                                      \
    BAR(); LGKM(4);  MFMA8(a1, b0, 1, 0, 0);                                   \
           LGKM(0);  MFMA8(a1, b0, 1, 0, 1); BAR();                            \
    /* ph3: B1 (4 reads) */                                                    \
    RDB(b1, BUF, 1, 0); SB(); RDB(b1, BUF, 1, 1); SB();                        \
    STG3;                                                                      \
    BAR(); LGKM(2);  MFMA8(a1, b1, 1, 1, 0);                                   \
           LGKM(0);  MFMA8(a1, b1, 1, 1, 1); BAR();                            \
    /* ph4: no reads, pure MFMA */                                             \
    STG4; WAIT4;                                                               \
    BAR();           MFMA8(a0, b1, 0, 1, 0);                                   \
                     MFMA8(a0, b1, 0, 1, 1); BAR();                            \
  }

  // Prologue: buf0 = kt0 full, buf1 = kt1 {B0, A1, B1} (A0 arrives iter0-ph1)
  STAGE_A(0, 0, 0); STAGE_B(0, 0, 0); STAGE_A(0, 0, 1); STAGE_B(0, 0, 1);
  STAGE_B(1, 1, 0); STAGE_A(1, 1, 1); STAGE_B(1, 1, 1);
  VM6(); BAR();

#pragma unroll 1
  for (int it = 0; it < 7; ++it) {
    const int kt = it * 2;
    KTILE(0, STAGE_A(1, kt + 1, 0), STAGE_B(0, kt + 2, 0),
             STAGE_A(0, kt + 2, 1), STAGE_B(0, kt + 2, 1), VM6());
    KTILE(1, STAGE_A(0, kt + 2, 0), STAGE_B(1, kt + 3, 0),
             STAGE_A(1, kt + 3, 1), STAGE_B(1, kt + 3, 1), VM6());
  }
  // last iteration (kt=14): only buf1.A0 (kt 15) still needs staging
  KTILE(0, STAGE_A(1, 15, 0), , , , VM0());
  KTILE(1, , , , , );

  // Epilogue: C/D col=lane&15, row=quad*4+reg. qkv[token*3072 + col].
#pragma unroll
  for (int nh = 0; nh < 4; ++nh) {
    const int col = n0 + wn4 * 64 + nh * 16 + lcol;
    const int seg = col >> 10, cs = col & 1023;
    const float bi = ((seg == 0) ? bq : (seg == 1) ? bk : bv)[cs];
#pragma unroll
    for (int mi = 0; mi < 8; ++mi) {
      const int r0 = m0 + wm2 * 128 + mi * 16 + quad * 4;
#pragma unroll
      for (int r = 0; r < 4; ++r)
        qkv[(size_t)(r0 + r) * 3072 + col] = (_Float16)(acc[mi][nh][r] + bi);
    }
  }
#undef STAGE_A
#undef STAGE_B
#undef RDA
#undef RDB
#undef MFMA8
#undef SB
#undef BAR
#undef LGKM
#undef VM6
#undef VM0
#undef KTILE
}

// One wave per token. qkv [token][3][1024] fp16. All global loads hoisted;
// pat read directly from global (L2-hot, no LDS/sync); PV uses 16x16x16 MFMA
// (K=16 exact: all 64 lanes active, no zero-padding, f16x4 operands).
__global__ __launch_bounds__(256) void attn_kernel(
    const _Float16* __restrict__ qkv,
    const float* __restrict__ pat,
    float* __restrict__ out)
{
  __shared__ __align__(16) _Float16 Ps[4][16 * 24];  // P[h][g], stride 24
  __shared__ __align__(16) _Float16 Vt[4][64 * 24];  // V^T[d][g], stride 24

  const int tid  = threadIdx.x;
  const int ln   = tid & 63;
  const int wv   = tid >> 6;
  const int lcol = ln & 15, quad = ln >> 4;
  const int t    = blockIdx.x * 4 + wv;

  const _Float16* qg = qkv + (size_t)t * 3072;
  const _Float16* kg = qg + 1024;
  const _Float16* vg = qg + 2048;

  // Issue every global load up front: V (2), Q (2), K (2), pat (4 scalar).
  f16x8 vc[2];
  vc[0] = *(const f16x8*)(vg + ((ln >> 3)    ) * 64 + (ln & 7) * 8);
  vc[1] = *(const f16x8*)(vg + ((ln >> 3) + 8) * 64 + (ln & 7) * 8);
  f16x8 aq0 = *(const f16x8*)(qg + lcol * 64 + quad * 8);
  f16x8 aq1 = *(const f16x8*)(qg + lcol * 64 + 32 + quad * 8);
  f16x8 bk0 = *(const f16x8*)(kg + lcol * 64 + quad * 8);
  f16x8 bk1 = *(const f16x8*)(kg + lcol * 64 + 32 + quad * 8);
  float p4[4];
#pragma unroll
  for (int r = 0; r < 4; r++) p4[r] = pat[(quad * 4 + r) * 16 + lcol];

  // Scatter V transposed into Vt[d][g] (wave-private, no barrier needed).
#pragma unroll
  for (int i = 0; i < 2; i++) {
    const int g = (ln >> 3) + i * 8, c = (ln & 7) * 8;
#pragma unroll
    for (int j = 0; j < 8; j++) Vt[wv][(c + j) * 24 + g] = vc[i][j];
  }

  // QK^T: A[m=h=lcol][k=quad*8+j], B[n=g=lcol][k=quad*8+j]
  f32x4 s = {0.f, 0.f, 0.f, 0.f};
  s = __builtin_amdgcn_mfma_f32_16x16x32_f16(aq0, bk0, s, 0, 0, 0);
  s = __builtin_amdgcn_mfma_f32_16x16x32_f16(aq1, bk1, s, 0, 0, 0);

  // lane holds scores[h=quad*4+r][g=lcol]; mask, softmax over g (16 lanes)
#pragma unroll
  for (int r = 0; r < 4; r++) {
    const float sv = s[r] * p4[r];
    float m = sv;
#pragma unroll
    for (int msk = 1; msk < 16; msk <<= 1) m = fmaxf(m, __shfl_xor(m, msk, 64));
    const float e = __expf(sv - m);
    float su = e;
#pragma unroll
    for (int msk = 1; msk < 16; msk <<= 1) su += __shfl_xor(su, msk, 64);
    Ps[wv][(quad * 4 + r) * 24 + lcol] = (_Float16)(e / su);
  }

  // PV with 16x16x16 (K=16): A[m=h=lcol][k=g=quad*4+j] from Ps;
  // B[n=d][k=g=quad*4+j] from Vt. All lanes active.
  f16x4 ap = *(const f16x4*)&Ps[wv][lcol * 24 + quad * 4];

  f32x4 o[4];
#pragma unroll
  for (int dt = 0; dt < 4; dt++) {
    f16x4 bvf = *(const f16x4*)&Vt[wv][(dt * 16 + lcol) * 24 + quad * 4];
    f32x4 z = {0.f, 0.f, 0.f, 0.f};
    o[dt] = __builtin_amdgcn_mfma_f32_16x16x16f16(ap, bvf, z, 0, 0, 0);
  }

  // C layout: row h=quad*4+r, col d=dt*16+lcol
  float* op = out + (size_t)t * 1024;
#pragma unroll
  for (int dt = 0; dt < 4; dt++)
#pragma unroll
    for (int r = 0; r < 4; r++)
      op[(quad * 4 + r) * 64 + dt * 16 + lcol] = o[dt][r];
}

extern "C" void kernel_launch(void* const* d_in, const int* in_sizes, int n_in,
                              void* d_out, int out_size, void* d_ws, size_t ws_size,
                              hipStream_t stream) {
  const float* x   = (const float*)d_in[0];
  const float* pat = (const float*)d_in[1];
  const float* Wq  = (const float*)d_in[2];
  const float* bq  = (const float*)d_in[3];
  const float* Wk  = (const float*)d_in[4];
  const float* bk  = (const float*)d_in[5];
  const float* Wv  = (const float*)d_in[6];
  const float* bv  = (const float*)d_in[7];

  // ws layout (f16 elements):
  //   qkvh [16384][3][1024]  @ 0           (96 MiB)
  //   xh   [16384][1024]     @ 50331648    (32 MiB)
  //   wh   [3][1024][1024]   @ 67108864    ( 6 MiB)   total ~134 MiB
  _Float16* qkvh = (_Float16*)d_ws;
  _Float16* xh   = qkvh + (size_t)50331648;
  _Float16* wh   = qkvh + (size_t)67108864;

  cvt_f32_f16<<<4096, 256, 0, stream>>>(x, xh, 4194304);
  cvt3_f32_f16<<<dim3(256, 3), 256, 0, stream>>>(Wq, Wk, Wv, wh, 262144);

  // 64 m-tiles x 12 n-tiles = 768 blocks, 512 threads (8 waves)
  gemm_qkv<<<768, 512, 0, stream>>>(xh, wh, bq, bk, bv, qkvh);
  attn_kernel<<<M_ / 4, 256, 0, stream>>>(qkvh, pat, (float*)d_out);
}